// Round 1
// baseline (564.527 us; speedup 1.0000x reference)
//
#include <hip/hip_runtime.h>
#include <math.h>

constexpr int PP = 8;    // phases
constexpr int MM = 12;   // movements
constexpr int NB = 32;   // samples per block
constexpr int NT = 256;  // threads per block (NB * PP)

__device__ __forceinline__ float sigmoidf_fast(float x) {
    float e = __expf(-x);
    return __builtin_amdgcn_rcpf(1.0f + e);
}

__global__ __launch_bounds__(NT, 4) void frap_kernel(
    const float* __restrict__ states,        // (B,13)
    const int*   __restrict__ p2m,           // (8,12)
    const int*   __restrict__ comp_mask,     // (8,7)
    const float* __restrict__ p_emb,         // (2,4)
    const float* __restrict__ d_W,           // (4,1)
    const float* __restrict__ d_b,           // (4)
    const float* __restrict__ lane_W,        // (16,8)
    const float* __restrict__ lane_b,        // (16)
    const float* __restrict__ lane_conv_W,   // (20,32)
    const float* __restrict__ lane_conv_b,   // (20)
    const float* __restrict__ rel_emb,       // (2,4)
    const float* __restrict__ rel_conv_W,    // (20,4)
    const float* __restrict__ rel_conv_b,    // (20)
    const float* __restrict__ hid_W,         // (20,20)
    const float* __restrict__ hid_b,         // (20)
    const float* __restrict__ merge_W,       // (1,20)
    const float* __restrict__ merge_b,       // (1)
    float* __restrict__ out,                 // (B,8)
    int B)
{
    __shared__ float rel_s[PP*(PP-1)*20];    // 1120 floats: rel[p][q][o]
    __shared__ float v_s[NB*PP*21];          // v vectors, stride 21 (bank-conflict pad)
    __shared__ float base_s[2][16];          // lane_b + lane_W[:,4:8]·sig(p_emb[c])
    __shared__ float sdem[NB][MM];           // demands
    __shared__ int   sact[NB];               // acts
    __shared__ int   smask[PP];              // p2m rows as bitmasks

    const int tid = threadIdx.x;

    // ---- block init: rel[p][q][o] = relu(rel_conv_W · relu(rel_emb[comp_mask]) + rel_conv_b)
    for (int idx = tid; idx < PP*(PP-1)*20; idx += NT) {
        int o  = idx % 20;
        int pq = idx / 20;
        int cmv = comp_mask[pq];
        float s = rel_conv_b[o];
        #pragma unroll
        for (int c = 0; c < 4; ++c) {
            float re = fmaxf(rel_emb[cmv*4 + c], 0.0f);
            s = fmaf(rel_conv_W[o*4 + c], re, s);
        }
        rel_s[idx] = fmaxf(s, 0.0f);
    }

    // base[c][h] = lane_b[h] + sum_k lane_W[h][4+k] * sigmoid(p_emb[c][k])
    if (tid < 32) {
        int c = tid >> 4, h = tid & 15;
        float s = lane_b[h];
        #pragma unroll
        for (int k = 0; k < 4; ++k) {
            float sg = sigmoidf_fast(p_emb[c*4 + k]);
            s = fmaf(lane_W[h*8 + 4 + k], sg, s);
        }
        base_s[c][h] = s;
    } else if (tid >= 64 && tid < 64 + PP) {
        int pp = tid - 64;
        int msk = 0;
        for (int m = 0; m < MM; ++m) msk |= (p2m[pp*MM + m] & 1) << m;
        smask[pp] = msk;
    }

    // stage states (coalesced)
    const int b0 = blockIdx.x * NB;
    for (int idx = tid; idx < NB*13; idx += NT) {
        int bb = idx / 13, col = idx - bb*13;
        float val = states[(size_t)(b0 + bb)*13 + col];
        if (col == 0) sact[bb] = (int)val;
        else          sdem[bb][col-1] = val;
    }

    __syncthreads();

    const int p  = tid & 7;
    const int bl = tid >> 3;
    const int b  = b0 + bl;

    const int act   = sact[bl];
    const int pmask = smask[p];
    const int cmask = smask[act];

    float dm[MM];
    #pragma unroll
    for (int m = 0; m < MM; ++m) dm[m] = sdem[bl][m];

    const float dw0 = d_W[0], dw1 = d_W[1], dw2 = d_W[2], dw3 = d_W[3];
    const float db0 = d_b[0], db1 = d_b[1], db2 = d_b[2], db3 = d_b[3];

    // ---- stage 1: agg[16] = sum_m relu(base[conn[m]] + lane_W[:,0:4]·sigmoid(x·d_W+d_b))
    float agg[16];
    #pragma unroll
    for (int h = 0; h < 16; ++h) agg[h] = 0.0f;

    #pragma unroll
    for (int m = 0; m < MM; ++m) {
        float x = ((pmask >> m) & 1) ? dm[m] : 0.0f;
        float e0 = sigmoidf_fast(fmaf(x, dw0, db0));
        float e1 = sigmoidf_fast(fmaf(x, dw1, db1));
        float e2 = sigmoidf_fast(fmaf(x, dw2, db2));
        float e3 = sigmoidf_fast(fmaf(x, dw3, db3));
        const float* bs = base_s[(cmask >> m) & 1];
        #pragma unroll
        for (int h = 0; h < 16; ++h) {
            float t = bs[h];
            t = fmaf(lane_W[h*8 + 0], e0, t);
            t = fmaf(lane_W[h*8 + 1], e1, t);
            t = fmaf(lane_W[h*8 + 2], e2, t);
            t = fmaf(lane_W[h*8 + 3], e3, t);
            agg[h] += fmaxf(t, 0.0f);
        }
    }

    // ---- stage 2: u = lane_conv_W[:, :16]·agg + b1 (regs), v = lane_conv_W[:,16:]·agg (LDS)
    float u[20];
    float* vout = &v_s[tid*21];
    #pragma unroll
    for (int o = 0; o < 20; ++o) {
        float su = lane_conv_b[o];
        float sv = 0.0f;
        #pragma unroll
        for (int h = 0; h < 16; ++h) {
            su = fmaf(lane_conv_W[o*32 + h],      agg[h], su);
            sv = fmaf(lane_conv_W[o*32 + 16 + h], agg[h], sv);
        }
        u[o]    = su;
        vout[o] = sv;
    }

    __syncthreads();

    // ---- stage 3: 7 pairs, rot = relu(u + v_j) * rel; c2 = relu(hid_W·rot + hid_b); q += merge·c2
    float q_acc = 7.0f * merge_b[0];

    for (int qi = 0; qi < 7; ++qi) {
        int j = qi + (qi >= p ? 1 : 0);
        const float* vj = &v_s[(bl*8 + j)*21];
        const float* rr = &rel_s[(p*7 + qi)*20];
        float rot[20];
        #pragma unroll
        for (int o = 0; o < 20; ++o) {
            rot[o] = fmaxf(u[o] + vj[o], 0.0f) * rr[o];
        }
        #pragma unroll
        for (int o2 = 0; o2 < 20; ++o2) {
            float s = hid_b[o2];
            #pragma unroll
            for (int o = 0; o < 20; ++o)
                s = fmaf(hid_W[o2*20 + o], rot[o], s);
            q_acc = fmaf(merge_W[o2], fmaxf(s, 0.0f), q_acc);
        }
    }

    if (b < B) out[(size_t)b*8 + p] = q_acc;
}

extern "C" void kernel_launch(void* const* d_in, const int* in_sizes, int n_in,
                              void* d_out, int out_size, void* d_ws, size_t ws_size,
                              hipStream_t stream) {
    const float* states       = (const float*)d_in[0];
    const int*   p2m          = (const int*)  d_in[1];
    // d_in[2] = oshape scalar (P=8, compile-time here)
    const int*   comp_mask    = (const int*)  d_in[3];
    const float* p_emb        = (const float*)d_in[4];
    const float* d_W          = (const float*)d_in[5];
    const float* d_b          = (const float*)d_in[6];
    const float* lane_W       = (const float*)d_in[7];
    const float* lane_b       = (const float*)d_in[8];
    const float* lane_conv_W  = (const float*)d_in[9];
    const float* lane_conv_b  = (const float*)d_in[10];
    const float* rel_emb      = (const float*)d_in[11];
    const float* rel_conv_W   = (const float*)d_in[12];
    const float* rel_conv_b   = (const float*)d_in[13];
    const float* hid_W        = (const float*)d_in[14];
    const float* hid_b        = (const float*)d_in[15];
    const float* merge_W      = (const float*)d_in[16];
    const float* merge_b      = (const float*)d_in[17];
    float* out = (float*)d_out;

    int B = in_sizes[0] / 13;
    int grid = (B + NB - 1) / NB;
    frap_kernel<<<grid, NT, 0, stream>>>(states, p2m, comp_mask, p_emb, d_W, d_b,
        lane_W, lane_b, lane_conv_W, lane_conv_b, rel_emb, rel_conv_W, rel_conv_b,
        hid_W, hid_b, merge_W, merge_b, out, B);
}

// Round 2
// 132.034 us; speedup vs baseline: 4.2756x; 4.2756x over previous
//
#include <hip/hip_runtime.h>
#include <math.h>

// ---- d_ws layout (float indices) ----
#define WS_H      0        // Hsel[p][qi][o2][o] : 8*7*20*20 = 22400
#define WS_HB     22400    // hid_b[20]
#define WS_MW     22420    // merge_W[20]
#define WS_MB     22440    // merge_b
#define WS_B0     22441    // base[2][16]
#define WS_Z0     22473    // zvec[2][16]
#define WS_W4     22505    // lane_W[:, :4] as [h][k] : 64
#define WS_DW     22569    // d_W 4
#define WS_DB     22573    // d_b 4
#define WS_WU     22577    // Wu[20][16]
#define WS_WV     22897    // Wv[20][16]
#define WS_UB     23217    // lane_conv_b[20]
#define WS_PM     23240    // int pmask[8]
#define WS_PJ     23248    // int pairj[8][7]
#define WS_CF     23304    // int cflag[8][7]
// total 23360 floats = 93,440 bytes

__global__ void frap_setup(
    const int* __restrict__ p2m, const int* __restrict__ comp_mask,
    const float* __restrict__ p_emb, const float* __restrict__ d_W, const float* __restrict__ d_b,
    const float* __restrict__ lane_W, const float* __restrict__ lane_b,
    const float* __restrict__ lane_conv_W, const float* __restrict__ lane_conv_b,
    const float* __restrict__ rel_emb, const float* __restrict__ rel_conv_W, const float* __restrict__ rel_conv_b,
    const float* __restrict__ hid_W, const float* __restrict__ hid_b,
    const float* __restrict__ merge_W, const float* __restrict__ merge_b,
    float* __restrict__ ws)
{
    __shared__ float R[2][20];
    __shared__ int cm[56];
    const int t = threadIdx.x;
    if (t < 40) {
        int c = t / 20, o = t % 20;
        float s = rel_conv_b[o];
        #pragma unroll
        for (int k = 0; k < 4; ++k)
            s = fmaf(rel_conv_W[o*4+k], fmaxf(rel_emb[c*4+k], 0.f), s);
        R[c][o] = fmaxf(s, 0.f);
    }
    if (t >= 64 && t < 120) cm[t-64] = comp_mask[t-64];
    __syncthreads();

    // Hsel[p][qi][o2][o] = hid_W[o2][o] * R[comp_mask[p][qi]][o]
    const int gsz = gridDim.x * blockDim.x;
    for (int i = blockIdx.x*blockDim.x + t; i < 8*7*400; i += gsz) {
        int o  = i % 20;
        int o2 = (i / 20) % 20;
        int pq = i / 400;
        ws[WS_H + i] = hid_W[o2*20 + o] * R[cm[pq]][o];
    }
    if (blockIdx.x != 0) return;

    if (t < 20) { ws[WS_HB+t] = hid_b[t]; ws[WS_MW+t] = merge_W[t]; ws[WS_UB+t] = lane_conv_b[t]; }
    if (t == 0) ws[WS_MB] = merge_b[0];
    if (t < 32) {
        int c = t >> 4, h = t & 15;
        float s = lane_b[h];
        #pragma unroll
        for (int k = 0; k < 4; ++k) {
            float sg = 1.f/(1.f + __expf(-p_emb[c*4+k]));
            s = fmaf(lane_W[h*8+4+k], sg, s);
        }
        ws[WS_B0 + c*16 + h] = s;              // base_c[h]
        float z = s;
        #pragma unroll
        for (int k = 0; k < 4; ++k) {
            float sg = 1.f/(1.f + __expf(-d_b[k]));
            z = fmaf(lane_W[h*8+k], sg, z);
        }
        ws[WS_Z0 + c*16 + h] = fmaxf(z, 0.f);  // zvec_c[h]
    }
    if (t < 64) ws[WS_W4 + t] = lane_W[(t>>2)*8 + (t&3)];
    if (t < 4) { ws[WS_DW+t] = d_W[t]; ws[WS_DB+t] = d_b[t]; }
    if (t >= 128 && t < 448) {
        int i = t - 128; int o = i >> 4, h = i & 15;
        ws[WS_WU + i] = lane_conv_W[o*32 + h];
        ws[WS_WV + i] = lane_conv_W[o*32 + 16 + h];
    }
    int* wi = (int*)ws;
    if (t < 8) { int mk = 0; for (int m = 0; m < 12; ++m) mk |= (p2m[t*12+m]&1) << m; wi[WS_PM+t] = mk; }
    if (t < 56) { int pp = t/7, qq = t%7; wi[WS_PJ+t] = qq + (qq >= pp ? 1 : 0); }
}

__global__ __launch_bounds__(512, 2) void frap_main(
    const float* __restrict__ states, const float* __restrict__ ws,
    float* __restrict__ out, int B)
{
    __shared__ float v_s[64*161];   // v[lane][p*20+o], stride 161 (odd mod 32 -> conflict-free)
    const int tid  = threadIdx.x;
    const int lane = tid & 63;
    const int p    = __builtin_amdgcn_readfirstlane(tid >> 6);  // wave-uniform phase
    const int b    = blockIdx.x * 64 + lane;
    const int bc   = b < B ? b : B - 1;
    const int* wi  = (const int*)ws;

    const float* srow = states + (size_t)bc * 13;
    const int cmask = wi[WS_PM + (int)srow[0]];   // connectivity mask of act (lane-varying)
    float dm[12];
    #pragma unroll
    for (int m = 0; m < 12; ++m) dm[m] = srow[1+m];

    const int pmask = wi[WS_PM + p];              // scalar

    // ---- stage 1: agg[16]
    float agg[16];
    #pragma unroll
    for (int h = 0; h < 16; ++h) agg[h] = 0.f;

    #pragma unroll
    for (int m = 0; m < 12; ++m) {
        const bool cbit = (cmask >> m) & 1;
        if ((pmask >> m) & 1) {                   // wave-uniform branch
            float e[4];
            #pragma unroll
            for (int k = 0; k < 4; ++k) {
                float xx = fmaf(dm[m], ws[WS_DW+k], ws[WS_DB+k]);
                e[k] = __builtin_amdgcn_rcpf(1.f + __expf(-xx));
            }
            #pragma unroll
            for (int h = 0; h < 16; ++h) {
                float t = cbit ? ws[WS_B0+16+h] : ws[WS_B0+h];
                #pragma unroll
                for (int k = 0; k < 4; ++k)
                    t = fmaf(ws[WS_W4 + h*4 + k], e[k], t);
                agg[h] += fmaxf(t, 0.f);
            }
        } else {
            #pragma unroll
            for (int h = 0; h < 16; ++h)
                agg[h] += cbit ? ws[WS_Z0+16+h] : ws[WS_Z0+h];
        }
    }

    // ---- stage 2: u (regs) + v (LDS)
    float u[20];
    #pragma unroll
    for (int o = 0; o < 20; ++o) {
        float su = ws[WS_UB + o];
        float sv = 0.f;
        #pragma unroll
        for (int h = 0; h < 16; ++h) {
            su = fmaf(ws[WS_WU + o*16 + h], agg[h], su);
            sv = fmaf(ws[WS_WV + o*16 + h], agg[h], sv);
        }
        u[o] = su;
        v_s[lane*161 + p*20 + o] = sv;
    }
    __syncthreads();

    // ---- stage 3: y[qi] = relu(u + v_j)  (rel folded into Hsel)
    float y[7][20];
    #pragma unroll
    for (int qi = 0; qi < 7; ++qi) {
        const int j = wi[WS_PJ + p*7 + qi];       // scalar
        const float* vj = &v_s[lane*161 + j*20];
        #pragma unroll
        for (int o = 0; o < 20; ++o)
            y[qi][o] = fmaxf(u[o] + vj[o], 0.f);
    }

    float q_acc = 7.f * ws[WS_MB];
    #pragma unroll
    for (int o2 = 0; o2 < 20; ++o2) {
        const float hb = ws[WS_HB + o2];
        const float mw = ws[WS_MW + o2];
        #pragma unroll
        for (int qi = 0; qi < 7; ++qi) {
            const float* Hrow = ws + WS_H + (p*7 + qi)*400 + o2*20;  // scalar ptr
            float s = hb;
            #pragma unroll
            for (int o = 0; o < 20; ++o)
                s = fmaf(Hrow[o], y[qi][o], s);
            q_acc = fmaf(mw, fmaxf(s, 0.f), q_acc);
        }
    }
    if (b < B) out[(size_t)b*8 + p] = q_acc;
}

extern "C" void kernel_launch(void* const* d_in, const int* in_sizes, int n_in,
                              void* d_out, int out_size, void* d_ws, size_t ws_size,
                              hipStream_t stream) {
    const float* states       = (const float*)d_in[0];
    const int*   p2m          = (const int*)  d_in[1];
    const int*   comp_mask    = (const int*)  d_in[3];
    const float* p_emb        = (const float*)d_in[4];
    const float* d_W          = (const float*)d_in[5];
    const float* d_b          = (const float*)d_in[6];
    const float* lane_W       = (const float*)d_in[7];
    const float* lane_b       = (const float*)d_in[8];
    const float* lane_conv_W  = (const float*)d_in[9];
    const float* lane_conv_b  = (const float*)d_in[10];
    const float* rel_emb      = (const float*)d_in[11];
    const float* rel_conv_W   = (const float*)d_in[12];
    const float* rel_conv_b   = (const float*)d_in[13];
    const float* hid_W        = (const float*)d_in[14];
    const float* hid_b        = (const float*)d_in[15];
    const float* merge_W      = (const float*)d_in[16];
    const float* merge_b      = (const float*)d_in[17];
    float* out = (float*)d_out;
    float* ws  = (float*)d_ws;

    frap_setup<<<64, 512, 0, stream>>>(p2m, comp_mask, p_emb, d_W, d_b, lane_W, lane_b,
        lane_conv_W, lane_conv_b, rel_emb, rel_conv_W, rel_conv_b, hid_W, hid_b,
        merge_W, merge_b, ws);

    int B = in_sizes[0] / 13;
    int grid = (B + 63) / 64;
    frap_main<<<grid, 512, 0, stream>>>(states, ws, out, B);
}

// Round 3
// 97.760 us; speedup vs baseline: 5.7746x; 1.3506x over previous
//
#include <hip/hip_runtime.h>
#include <math.h>

// ---- d_ws layout (float indices) ----
#define WS_H      0        // Hsel[p][qi][o2][o] : 8*7*20*20 = 22400
#define WS_HB     22400    // hid_b[20]
#define WS_MW     22420    // merge_W[20]
#define WS_MB     22440    // merge_b
#define WS_B0     22441    // base[2][16]
#define WS_Z0     22473    // zvec[2][16]
#define WS_W4     22505    // lane_W[:, :4] as [h][k] : 64
#define WS_DW     22569    // d_W 4
#define WS_DB     22573    // d_b 4
#define WS_WU     22577    // Wu[20][16]
#define WS_WV     22897    // Wv[20][16]
#define WS_UB     23217    // lane_conv_b[20]
#define WS_PM     23240    // int pmask[8]
#define WS_PJ     23248    // int pairj[8][7]
// total ~23304 floats = 93,216 bytes

__global__ void frap_setup(
    const int* __restrict__ p2m, const int* __restrict__ comp_mask,
    const float* __restrict__ p_emb, const float* __restrict__ d_W, const float* __restrict__ d_b,
    const float* __restrict__ lane_W, const float* __restrict__ lane_b,
    const float* __restrict__ lane_conv_W, const float* __restrict__ lane_conv_b,
    const float* __restrict__ rel_emb, const float* __restrict__ rel_conv_W, const float* __restrict__ rel_conv_b,
    const float* __restrict__ hid_W, const float* __restrict__ hid_b,
    const float* __restrict__ merge_W, const float* __restrict__ merge_b,
    float* __restrict__ ws)
{
    __shared__ float R[2][20];
    __shared__ int cm[56];
    const int t = threadIdx.x;
    if (t < 40) {
        int c = t / 20, o = t % 20;
        float s = rel_conv_b[o];
        #pragma unroll
        for (int k = 0; k < 4; ++k)
            s = fmaf(rel_conv_W[o*4+k], fmaxf(rel_emb[c*4+k], 0.f), s);
        R[c][o] = fmaxf(s, 0.f);
    }
    if (t >= 64 && t < 120) cm[t-64] = comp_mask[t-64];
    __syncthreads();

    // Hsel[p][qi][o2][o] = hid_W[o2][o] * R[comp_mask[p][qi]][o]
    const int gsz = gridDim.x * blockDim.x;
    for (int i = blockIdx.x*blockDim.x + t; i < 8*7*400; i += gsz) {
        int o  = i % 20;
        int o2 = (i / 20) % 20;
        int pq = i / 400;
        ws[WS_H + i] = hid_W[o2*20 + o] * R[cm[pq]][o];
    }
    if (blockIdx.x != 0) return;

    if (t < 20) { ws[WS_HB+t] = hid_b[t]; ws[WS_MW+t] = merge_W[t]; ws[WS_UB+t] = lane_conv_b[t]; }
    if (t == 0) ws[WS_MB] = merge_b[0];
    if (t < 32) {
        int c = t >> 4, h = t & 15;
        float s = lane_b[h];
        #pragma unroll
        for (int k = 0; k < 4; ++k) {
            float sg = 1.f/(1.f + __expf(-p_emb[c*4+k]));
            s = fmaf(lane_W[h*8+4+k], sg, s);
        }
        ws[WS_B0 + c*16 + h] = s;              // base_c[h]
        float z = s;
        #pragma unroll
        for (int k = 0; k < 4; ++k) {
            float sg = 1.f/(1.f + __expf(-d_b[k]));
            z = fmaf(lane_W[h*8+k], sg, z);
        }
        ws[WS_Z0 + c*16 + h] = fmaxf(z, 0.f);  // zvec_c[h]
    }
    if (t < 64) ws[WS_W4 + t] = lane_W[(t>>2)*8 + (t&3)];
    if (t < 4) { ws[WS_DW+t] = d_W[t]; ws[WS_DB+t] = d_b[t]; }
    if (t >= 128 && t < 448) {
        int i = t - 128; int o = i >> 4, h = i & 15;
        ws[WS_WU + i] = lane_conv_W[o*32 + h];
        ws[WS_WV + i] = lane_conv_W[o*32 + 16 + h];
    }
    int* wi = (int*)ws;
    if (t < 8) { int mk = 0; for (int m = 0; m < 12; ++m) mk |= (p2m[t*12+m]&1) << m; wi[WS_PM+t] = mk; }
    if (t < 56) { int pp = t/7, qq = t%7; wi[WS_PJ+t] = qq + (qq >= pp ? 1 : 0); }
}

__global__ __launch_bounds__(512, 6) void frap_main(
    const float* __restrict__ states, const float* __restrict__ ws,
    float* __restrict__ out, int B)
{
    // v[(p*64+lane)*20 + o] : per-thread contiguous 80B, 16B aligned,
    // lane stride 20 words -> start bank 4*(5*lane mod 8): conflict-free b128.
    __shared__ float v_s[8*64*20];          // 40,960 B -> 3 blocks/CU
    const int tid  = threadIdx.x;
    const int lane = tid & 63;
    const int p    = __builtin_amdgcn_readfirstlane(tid >> 6);  // wave-uniform phase
    const int b    = blockIdx.x * 64 + lane;
    const int bc   = b < B ? b : B - 1;
    const int* wi  = (const int*)ws;

    const float* srow = states + (size_t)bc * 13;
    const int cmask = wi[WS_PM + (int)srow[0]];   // act's connectivity (lane-varying)
    float dm[12];
    #pragma unroll
    for (int m = 0; m < 12; ++m) dm[m] = srow[1+m];

    const int pmask = wi[WS_PM + p];              // scalar

    // ---- stage 1: agg[16]
    // unconnected movements folded: count them per embed class, 2 FMA/h
    const int notp = ~pmask & 0xFFF;
    const float cnt1 = (float)__popc(cmask & notp);
    const float cnt0 = (float)__popc(~cmask & notp);

    float agg[16];
    #pragma unroll
    for (int h = 0; h < 16; ++h)
        agg[h] = fmaf(cnt0, ws[WS_Z0+h], cnt1 * ws[WS_Z0+16+h]);

    #pragma unroll
    for (int m = 0; m < 12; ++m) {
        if ((pmask >> m) & 1) {                   // wave-uniform branch
            const bool cbit = (cmask >> m) & 1;
            float e[4];
            #pragma unroll
            for (int k = 0; k < 4; ++k) {
                float xx = fmaf(dm[m], ws[WS_DW+k], ws[WS_DB+k]);
                e[k] = __builtin_amdgcn_rcpf(1.f + __expf(-xx));
            }
            #pragma unroll
            for (int h = 0; h < 16; ++h) {
                float t = cbit ? ws[WS_B0+16+h] : ws[WS_B0+h];
                #pragma unroll
                for (int k = 0; k < 4; ++k)
                    t = fmaf(ws[WS_W4 + h*4 + k], e[k], t);
                agg[h] += fmaxf(t, 0.f);
            }
        }
    }

    // ---- stage 2: u (regs) + v (LDS, vectorized writes)
    float u[20], sv[20];
    #pragma unroll
    for (int o = 0; o < 20; ++o) {
        float su = ws[WS_UB + o];
        float s2 = 0.f;
        #pragma unroll
        for (int h = 0; h < 16; ++h) {
            su = fmaf(ws[WS_WU + o*16 + h], agg[h], su);
            s2 = fmaf(ws[WS_WV + o*16 + h], agg[h], s2);
        }
        u[o]  = su;
        sv[o] = s2;
    }
    {
        float* vdst = &v_s[(p*64 + lane)*20];
        #pragma unroll
        for (int o = 0; o < 20; o += 4) {
            float4 t4; t4.x = sv[o]; t4.y = sv[o+1]; t4.z = sv[o+2]; t4.w = sv[o+3];
            *(float4*)(vdst + o) = t4;
        }
    }
    __syncthreads();

    // ---- stage 3: qi-outer; y[20] live per pair only
    float q_acc = 7.f * ws[WS_MB];
    for (int qi = 0; qi < 7; ++qi) {
        const int j = wi[WS_PJ + p*7 + qi];       // scalar
        const float* vj = &v_s[(j*64 + lane)*20];
        float y[20];
        #pragma unroll
        for (int o = 0; o < 20; o += 4) {
            float4 t4 = *(const float4*)(vj + o);
            y[o]   = fmaxf(u[o]   + t4.x, 0.f);
            y[o+1] = fmaxf(u[o+1] + t4.y, 0.f);
            y[o+2] = fmaxf(u[o+2] + t4.z, 0.f);
            y[o+3] = fmaxf(u[o+3] + t4.w, 0.f);
        }
        const float* Hbase = ws + WS_H + (p*7 + qi)*400;   // scalar ptr
        #pragma unroll
        for (int o2 = 0; o2 < 20; ++o2) {
            float s = ws[WS_HB + o2];
            #pragma unroll
            for (int o = 0; o < 20; ++o)
                s = fmaf(Hbase[o2*20 + o], y[o], s);
            q_acc = fmaf(ws[WS_MW + o2], fmaxf(s, 0.f), q_acc);
        }
    }
    if (b < B) out[(size_t)b*8 + p] = q_acc;
}

extern "C" void kernel_launch(void* const* d_in, const int* in_sizes, int n_in,
                              void* d_out, int out_size, void* d_ws, size_t ws_size,
                              hipStream_t stream) {
    const float* states       = (const float*)d_in[0];
    const int*   p2m          = (const int*)  d_in[1];
    const int*   comp_mask    = (const int*)  d_in[3];
    const float* p_emb        = (const float*)d_in[4];
    const float* d_W          = (const float*)d_in[5];
    const float* d_b          = (const float*)d_in[6];
    const float* lane_W       = (const float*)d_in[7];
    const float* lane_b       = (const float*)d_in[8];
    const float* lane_conv_W  = (const float*)d_in[9];
    const float* lane_conv_b  = (const float*)d_in[10];
    const float* rel_emb      = (const float*)d_in[11];
    const float* rel_conv_W   = (const float*)d_in[12];
    const float* rel_conv_b   = (const float*)d_in[13];
    const float* hid_W        = (const float*)d_in[14];
    const float* hid_b        = (const float*)d_in[15];
    const float* merge_W      = (const float*)d_in[16];
    const float* merge_b      = (const float*)d_in[17];
    float* out = (float*)d_out;
    float* ws  = (float*)d_ws;

    frap_setup<<<64, 512, 0, stream>>>(p2m, comp_mask, p_emb, d_W, d_b, lane_W, lane_b,
        lane_conv_W, lane_conv_b, rel_emb, rel_conv_W, rel_conv_b, hid_W, hid_b,
        merge_W, merge_b, ws);

    int B = in_sizes[0] / 13;
    int grid = (B + 63) / 64;
    frap_main<<<grid, 512, 0, stream>>>(states, ws, out, B);
}